// Round 1
// 17821.046 us; speedup vs baseline: 1.2317x; 1.2317x over previous
//
#include <hip/hip_runtime.h>
#include <math.h>

#define NOPS 7
#define KITERS 3
#define NBLK 31   // perm-blocks; 31 blocks x 4 rounds = 124 rounds = exactly 4 full sweeps

// XOR-mask lane exchange within 32-lane groups (bitmode swizzle)
template<int M>
__device__ __forceinline__ float swz(float x) {
    return __int_as_float(__builtin_amdgcn_ds_swizzle(__float_as_int(x), (M << 10) | 0x1F));
}
__device__ __forceinline__ float bperm(int addr, float x) {
    return __int_as_float(__builtin_amdgcn_ds_bpermute(addr, __float_as_int(x)));
}

// One parallel Jacobi round with pairing {x, x^M}: M' = J^T M J, V <- V J.
// Register layout: a[k] = M[row][row^k] (xor-aligned), v[k] = V[row][k] (plain slots).
template<int M>
__device__ __forceinline__ void jround(float (&a)[32], float (&v)[32], float2* ct, const int il) {
    const int fil = (il & (M - 1)) | ((il >> 1) & ~(M - 1));   // own pair id (delete bit log2 M)
    const float dq  = swz<M>(a[0]);    // partner's diagonal
    const float apq = a[M];            // own pair off-diagonal
    float c = 1.f, s = 0.f;
    if (fabsf(apq) > 1e-12f) {
        const float th = (dq - a[0]) / (2.f * apq);   // valid on writer (p-role) lanes
        const float t  = copysignf(1.f, th) / (fabsf(th) + sqrtf(1.f + th * th));
        c = rsqrtf(1.f + t * t);
        s = t * c;
    }
    if ((il & M) == 0) ct[fil] = make_float2(c, s);    // single writer per pair
    __syncthreads();
    const float sg = (il & M) ? 1.f : -1.f;
    float c0 = 1.f, s0 = 0.f;
    // column rotations on M (regs pair (k,k^M) = slot-cols (il^k, il^k^M)) and on V (slot pair (k,k^M))
    #pragma unroll
    for (int k = 0; k < 32; ++k) {
        if (k & M) continue;
        const int fk = (k & (M - 1)) | ((k >> 1) & ~(M - 1));
        const float2 cs = ct[fil ^ fk];    // angle of column-pair {il^k, il^k^M}
        const float sl = sg * cs.y;
        const float ak = a[k], am = a[k ^ M];
        a[k]     = fmaf( sl, am, cs.x * ak);
        a[k ^ M] = fmaf(-sl, ak, cs.x * am);
        const float2 cu = ct[fk];          // angle of slot pair {k, k^M} (uniform)
        const float vk = v[k], vm = v[k ^ M];
        v[k]     = fmaf(-cu.y, vm, cu.x * vk);
        v[k ^ M] = fmaf( cu.y, vk, cu.x * vm);
        if (k == 0) { c0 = cs.x; s0 = sl; }
    }
    // row mix: own' = c0*own + s0*partner (reads partner's post-colrot regs; pairwise = no big temp)
    #pragma unroll
    for (int k = 0; k < 32; ++k) {
        if (k & M) continue;
        const float r1 = swz<M>(a[k ^ M]);   // partner's value for my column il^k
        const float r2 = swz<M>(a[k]);       // partner's value for my column il^k^M
        a[k]     = fmaf(s0, r1, c0 * a[k]);
        a[k ^ M] = fmaf(s0, r2, c0 * a[k ^ M]);
    }
}

// slot permutation by L^4 (L = companion matrix of x^5+x^2+1, primitive):
// new[k](lane il) = old[L4(k)](lane L4(il)).  CYC walks the 31-cycle of L4.
__device__ __forceinline__ void perm4(float (&a)[32], float (&v)[32], const int paddr) {
    constexpr int CYC[31] = {1,16,13,14,27,12,30,22,2,5,26,28,19,24,25,9,
                             4,10,17,29,3,21,23,18,8,20,7,31,6,15,11};
    a[0] = bperm(paddr, a[0]);
    const float ta = a[CYC[0]];
    #pragma unroll
    for (int i = 0; i < 30; ++i) a[CYC[i]] = bperm(paddr, a[CYC[i + 1]]);
    a[CYC[30]] = bperm(paddr, ta);
    const float tv = v[CYC[0]];        // V: columns rename only (rows never move)
    #pragma unroll
    for (int i = 0; i < 30; ++i) v[CYC[i]] = v[CYC[i + 1]];
    v[CYC[30]] = tv;
}

// broadcast-read one 32-float row (uniform address, 8x ds_read_b128)
__device__ __forceinline__ void ldrow(const float* buf, const int j, float (&b)[32]) {
    const float4* p = (const float4*)(buf + (j << 5));
    #pragma unroll
    for (int cč = 0; cč < 8; ++cč) {
        const float4 t = p[cč];
        b[4 * cč] = t.x; b[4 * cč + 1] = t.y; b[4 * cč + 2] = t.z; b[4 * cč + 3] = t.w;
    }
}

__global__ __launch_bounds__(64, 2)
void karcher_kernel(const float* __restrict__ spds, const float* __restrict__ alphas,
                    float* __restrict__ out, int Mtot) {
    __shared__ __align__(16) float XIb[2][1024];   // staged Xih (then E)
    __shared__ __align__(16) float SCb[2][1024];   // scratch stage
    __shared__ float2 CTb[2][16];                  // rotation table
    __shared__ float FDb[2][32];                   // f(lambda) broadcast table
    __shared__ float GDb[2][32];
    __shared__ float WS[8];

    const int lane = threadIdx.x;
    const int il = lane & 31;        // row slot
    const int h  = lane >> 5;        // which matrix of the pair
    const int mat = blockIdx.x * 2 + h;
    const bool rr = (il < 30) && (mat < Mtot);

    float* XI = XIb[h];
    float* SC = SCb[h];
    float2* CT = CTb[h];
    float* fda = FDb[h];
    float* fdb = GDb[h];

    if (lane == 0) {   // softmax(alphas) -> WS
        float a[NOPS], mx = -1e30f, sum = 0.f;
        for (int o = 0; o < NOPS; ++o) { a[o] = alphas[o]; mx = fmaxf(mx, a[o]); }
        for (int o = 0; o < NOPS; ++o) { a[o] = expf(a[o] - mx); sum += a[o]; }
        for (int o = 0; o < NOPS; ++o) WS[o] = a[o] / sum;
    }

    // bpermute address for the L^4 row permutation (stay within own 32-lane half)
    int l4 = il;
    #pragma unroll
    for (int i = 0; i < 4; ++i) l4 = ((l4 << 1) & 31) ^ (((l4 >> 4) & 1) ? 5 : 0);
    const int paddr = ((lane & 32) | l4) << 2;

    const size_t ostr = (size_t)Mtot * 900;
    const float* Arow = spds + (size_t)mat * 900 + (size_t)il * 30;
    float* park = out + (size_t)mat * 900 + (size_t)il * 30;   // Xh parking + final output row

    auto stage_T = [&](float* buf, const float (&r)[32]) {     // buf[t][il] = r[t]  (bank=il, CF)
        #pragma unroll
        for (int t = 0; t < 32; ++t) buf[(t << 5) + il] = r[t];
    };
    auto xload = [&](const float* buf, float (&a)[32]) {       // a[k] = M[il][il^k] (bank=il, CF)
        #pragma unroll
        for (int k = 0; k < 32; ++k) a[k] = buf[((il ^ k) << 5) + il];
    };
    auto jacobi = [&](float (&a)[32], float (&v)[32]) {
        #pragma unroll
        for (int k = 0; k < 32; ++k) v[k] = (k == il) ? 1.f : 0.f;
        #pragma unroll 1
        for (int b = 0; b < NBLK; ++b) {
            jround<1>(a, v, CT, il);
            jround<2>(a, v, CT, il);
            jround<4>(a, v, CT, il);
            jround<8>(a, v, CT, il);
            perm4(a, v, paddr);
        }
    };

    __syncthreads();   // WS visible

    // ---- X = sum_o w_o A_o (plain rows; dummy rows/cols stay exactly 0) ----
    float X[32];
    #pragma unroll
    for (int t = 0; t < 32; ++t) X[t] = 0.f;
    if (rr) {
        #pragma unroll 1
        for (int o = 0; o < NOPS; ++o) {
            const float* Ao = Arow + o * ostr;
            const float wo = WS[o];
            #pragma unroll
            for (int u = 0; u < 15; ++u) {
                const float2 p = *(const float2*)(Ao + 2 * u);
                X[2 * u]     = fmaf(wo, p.x, X[2 * u]);
                X[2 * u + 1] = fmaf(wo, p.y, X[2 * u + 1]);
            }
        }
    }

    float Lacc[32];

    #pragma unroll 1
    for (int it = 0; it < KITERS; ++it) {
        // ---- eigh(X) ----
        __syncthreads();
        stage_T(SC, X);
        __syncthreads();
        float a1[32], v1[32];
        xload(SC, a1);
        jacobi(a1, v1);
        const float lam = fmaxf(a1[0], 1e-8f);
        const float sq = sqrtf(lam);
        fda[il] = sq;
        fdb[il] = 1.f / sq;
        __syncthreads();
        stage_T(SC, v1);                 // SC = V^T
        __syncthreads();
        // ---- Xh, Xih reconstruction ----
        float xh[32], xi[32];
        #pragma unroll
        for (int t = 0; t < 32; ++t) { xh[t] = 0.f; xi[t] = 0.f; }
        #pragma unroll 1
        for (int k = 0; k < 32; ++k) {
            const float vk = SC[(k << 5) + il];   // V[il][k]
            const float c1 = fda[k] * vk;
            const float c2 = fdb[k] * vk;
            float b[32]; ldrow(SC, k, b);         // V[t][k]
            #pragma unroll
            for (int t = 0; t < 32; ++t) {
                xh[t] = fmaf(c1, b[t], xh[t]);
                xi[t] = fmaf(c2, b[t], xi[t]);
            }
        }
        if (rr) {   // park Xh row in out[] (each lane round-trips only its own row)
            #pragma unroll
            for (int u = 0; u < 15; ++u)
                *(float2*)(park + 2 * u) = make_float2(xh[2 * u], xh[2 * u + 1]);
        }
        __syncthreads();
        stage_T(XI, xi);                 // XI = Xih (symmetric)
        #pragma unroll
        for (int t = 0; t < 32; ++t) Lacc[t] = 0.f;

        // ---- op loop: Lacc += w_o * logm(Xih A_o Xih) ----
        #pragma unroll 1
        for (int o = 0; o < NOPS; ++o) {
            float ar[32];
            #pragma unroll
            for (int t = 0; t < 32; ++t) ar[t] = 0.f;
            if (rr) {
                const float* Ao = Arow + o * ostr;
                #pragma unroll
                for (int u = 0; u < 15; ++u) {
                    const float2 p = *(const float2*)(Ao + 2 * u);
                    ar[2 * u] = p.x; ar[2 * u + 1] = p.y;
                }
            }
            __syncthreads();
            stage_T(SC, ar);             // SC = A_o (symmetric)
            __syncthreads();
            // T = Xih * A_o   (A-side: per-lane scalar from XI; B-side: broadcast rows of SC)
            float T[32];
            #pragma unroll
            for (int t = 0; t < 32; ++t) T[t] = 0.f;
            #pragma unroll 1
            for (int j = 0; j < 30; ++j) {
                const float av = XI[(j << 5) + il];   // Xih[il][j]
                float b[32]; ldrow(SC, j, b);
                #pragma unroll
                for (int t = 0; t < 32; ++t) T[t] = fmaf(av, b[t], T[t]);
            }
            // mid = T * Xih   (A-side: T regs static -> unrolled; B-side: broadcast XI rows)
            float mid[32];
            #pragma unroll
            for (int t = 0; t < 32; ++t) mid[t] = 0.f;
            #pragma unroll
            for (int j = 0; j < 30; ++j) {
                float b[32]; ldrow(XI, j, b);
                #pragma unroll
                for (int t = 0; t < 32; ++t) mid[t] = fmaf(T[j], b[t], mid[t]);
            }
            __syncthreads();
            stage_T(SC, mid);
            __syncthreads();
            float a2[32], v2[32];
            xload(SC, a2);
            jacobi(a2, v2);
            fda[il] = logf(fmaxf(a2[0], 1e-8f));
            __syncthreads();
            stage_T(SC, v2);             // SC = V^T of mid
            __syncthreads();
            const float wo = WS[o];
            #pragma unroll 1
            for (int k = 0; k < 32; ++k) {
                const float coef = wo * fda[k] * SC[(k << 5) + il];
                float b[32]; ldrow(SC, k, b);
                #pragma unroll
                for (int t = 0; t < 32; ++t) Lacc[t] = fmaf(coef, b[t], Lacc[t]);
            }
        }

        // ---- E = expm(L); X' = Xh E Xh ----
        __syncthreads();
        stage_T(SC, Lacc);
        __syncthreads();
        float a3[32], v3[32];
        xload(SC, a3);
        jacobi(a3, v3);
        fda[il] = expf(fmaxf(a3[0], 1e-8f));   // reference clamps eigenvalues before exp too
        __syncthreads();
        stage_T(SC, v3);
        __syncthreads();
        float E[32];
        #pragma unroll
        for (int t = 0; t < 32; ++t) E[t] = 0.f;
        #pragma unroll 1
        for (int k = 0; k < 32; ++k) {
            const float coef = fda[k] * SC[(k << 5) + il];
            float b[32]; ldrow(SC, k, b);
            #pragma unroll
            for (int t = 0; t < 32; ++t) E[t] = fmaf(coef, b[t], E[t]);
        }
        __syncthreads();
        stage_T(XI, E);                  // XI = E (Xih dead)
        float xr[32];                    // un-park Xh row
        #pragma unroll
        for (int t = 0; t < 32; ++t) xr[t] = 0.f;
        if (rr) {
            #pragma unroll
            for (int u = 0; u < 15; ++u) {
                const float2 p = *(const float2*)(park + 2 * u);
                xr[2 * u] = p.x; xr[2 * u + 1] = p.y;
            }
        }
        __syncthreads();
        float T2[32];                    // T2 = Xh * E
        #pragma unroll
        for (int t = 0; t < 32; ++t) T2[t] = 0.f;
        #pragma unroll
        for (int j = 0; j < 30; ++j) {
            float b[32]; ldrow(XI, j, b);
            #pragma unroll
            for (int t = 0; t < 32; ++t) T2[t] = fmaf(xr[j], b[t], T2[t]);
        }
        __syncthreads();
        stage_T(SC, xr);                 // SC = Xh
        __syncthreads();
        #pragma unroll
        for (int t = 0; t < 32; ++t) X[t] = 0.f;   // X' = T2 * Xh
        #pragma unroll
        for (int j = 0; j < 30; ++j) {
            float b[32]; ldrow(SC, j, b);
            #pragma unroll
            for (int t = 0; t < 32; ++t) X[t] = fmaf(T2[j], b[t], X[t]);
        }
    }

    if (rr) {
        #pragma unroll
        for (int u = 0; u < 15; ++u)
            *(float2*)(park + 2 * u) = make_float2(X[2 * u], X[2 * u + 1]);
    }
}

extern "C" void kernel_launch(void* const* d_in, const int* in_sizes, int n_in,
                              void* d_out, int out_size, void* d_ws, size_t ws_size,
                              hipStream_t stream) {
    const float* spds   = (const float*)d_in[0];
    const float* alphas = (const float*)d_in[1];
    float* out = (float*)d_out;
    const int Mtot = in_sizes[0] / (NOPS * 900);   // 8192
    karcher_kernel<<<dim3((Mtot + 1) / 2), dim3(64), 0, stream>>>(spds, alphas, out, Mtot);
}